// Round 16
// baseline (230.509 us; speedup 1.0000x reference)
//
#include <hip/hip_runtime.h>
#include <hip/hip_fp16.h>
#include <stdint.h>

#define K_DIM 4096
#define N_OUT 4096
#define BM 256
#define BN 256
#define BKB 64  // K-bytes per step = 2 MFMA K-slices

typedef __attribute__((ext_vector_type(4))) int int32x4;
typedef __attribute__((ext_vector_type(16))) int int32x16;

// ---------------- per-token int4 activation quantization ----------------
// x_scale = max(x_max/7, fp16(1e-5)); x_q = clip(rint(x/x_scale), -8, 7).
// All f32; no intermediate fp16 rounding (matches harness np reference).
__global__ __launch_bounds__(256) void quant_x(const float* __restrict__ x,
                                               int8_t* __restrict__ xq,
                                               float* __restrict__ xs) {
  const int row = blockIdx.x;
  const int t = threadIdx.x;
  const float4* xr = (const float4*)(x + (size_t)row * K_DIM);
  float4 v[4];
  float m = 0.f;
#pragma unroll
  for (int i = 0; i < 4; ++i) {
    v[i] = xr[t * 4 + i];
    m = fmaxf(m, fmaxf(fmaxf(fabsf(v[i].x), fabsf(v[i].y)),
                       fmaxf(fabsf(v[i].z), fabsf(v[i].w))));
  }
#pragma unroll
  for (int off = 32; off > 0; off >>= 1) m = fmaxf(m, __shfl_xor(m, off));
  __shared__ float wmax[4];
  if ((t & 63) == 0) wmax[t >> 6] = m;
  __syncthreads();
  m = fmaxf(fmaxf(wmax[0], wmax[1]), fmaxf(wmax[2], wmax[3]));

  const float eps = 1.0013580322265625e-05f;  // fp16(1e-5) as f32
  const float xscale = fmaxf(m / 7.0f, eps);
  if (t == 0) xs[row] = xscale;

  uint32_t p[4];
#pragma unroll
  for (int g = 0; g < 4; ++g) {
    const float* fv = (const float*)&v[g];
    uint32_t w = 0;
#pragma unroll
    for (int j = 0; j < 4; ++j) {
      float r = rintf(fv[j] / xscale);
      r = fminf(fmaxf(r, -8.f), 7.f);
      w |= ((uint32_t)(uint8_t)(int8_t)(int)r) << (8 * j);
    }
    p[g] = w;
  }
  *(uint4*)(xq + (size_t)row * K_DIM + t * 16) = *(uint4*)p;
}

// ---------------- weight pack: int32 -> int8, FRAGMENT-MAJOR ----------------
// block b = nfrag*128 + kslice; each block 1024B in MFMA lane order.
__global__ __launch_bounds__(256) void pack_w(const int* __restrict__ w,
                                              uint32_t* __restrict__ wqf) {
  const int c = blockIdx.x * 256 + threadIdx.x;  // one thread per 16B chunk
  const int blk = c >> 6;
  const int l = c & 63;
  const int row = ((blk >> 7) << 5) + (l & 31);
  const int k = ((blk & 127) << 5) + ((l >> 5) << 4);
  const int4* src = (const int4*)(w + (size_t)row * K_DIM + k);  // 16 ints
  uint32_t p[4];
#pragma unroll
  for (int g = 0; g < 4; ++g) {
    const int4 v = src[g];
    p[g] = (uint32_t)(v.x & 255) | ((uint32_t)(v.y & 255) << 8) |
           ((uint32_t)(v.z & 255) << 16) | ((uint32_t)(v.w & 255) << 24);
  }
  *(uint4*)(wqf + (size_t)c * 4) = *(uint4*)p;
}

// ---------------- i8 GEMM: out = dequant(xq . wq^T) ----------------
// r16 = r14's phase discipline (the proven +20%: barrier -> lgkmcnt(0) ->
// sched_barrier(0) -> setprio around each 8-MFMA cluster) + B moved from LDS
// back to frag-major global->register double-buffer (halves LDS reads to
// A-only 64KB/step/CU, removes B staging writes; B rides L2).
// 256x256 tile, 8 waves (2m x 4n), wave tile 128x64, 32x32x32 i8, BK=64B.
// Per step: P1 {4 A ds_reads | stageA(s+1) x2 | OPEN | 8 MFMA (ks0) | bar}
//           P2 {4 A ds_reads | loadB(s+1) x4 | OPEN | 8 MFMA (ks1) |
//               vmcnt(4) | bar}
// vmcnt ledger: end-of-step outstanding = [stageA(s+1)x2, loadB(s+1)x4];
// vmcnt(4) retires exactly stageA(s+1); loadB(s+1) drains via the
// compiler's reg-dep wait in next step's P1 (issued a full body earlier).
// Never vmcnt(0) in the loop.
__global__ __launch_bounds__(512, 2) void gemm_w4a4(
    const int8_t* __restrict__ xq, const uint8_t* __restrict__ wqf,
    const float* __restrict__ xs, const float* __restrict__ wscale,
    float* __restrict__ out, int M) {
  __shared__ uint8_t lds[2][16384];  // A only: 16 blk (8 fa x 2 ks) x 1KB /buf

  // Swizzle (validated r8): A-panels XCD-exclusive, L2-resident.
  const int bid = blockIdx.x;
  const int xcd = bid & 7;
  const int i_loc = bid >> 3;            // 0..63
  const int mt = xcd * 4 + (i_loc & 3);  // 0..31, XCD-exclusive
  const int nt = i_loc >> 2;             // 0..15
  const int tm = mt * BM;
  const int tn = nt * BN;

  const int t = threadIdx.x;  // 0..511
  const int l = t & 63;
  const int wv = t >> 6;      // 0..7
  const int wm = wv >> 2;     // 0..1
  const int wn = wv & 3;      // 0..3

  // A staging source (validated lane map): row (l&31), k-chunk (l>>5)*16
  const uint8_t* gA = (const uint8_t*)xq +
                      (size_t)(tm + wv * 32 + (l & 31)) * K_DIM +
                      ((l >> 5) << 4);
  // B fragment-major bases for this wave's two n-frags
  const int nfrag0 = nt * 8 + wn * 2;
  const uint8_t* gB0 = wqf + ((size_t)(nfrag0 * 128) << 10) + l * 16;
  const uint8_t* gB1 = wqf + ((size_t)((nfrag0 + 1) * 128) << 10) + l * 16;

  int32x16 acc[4][2] = {};

  // stage A of step ss into buf: blocks (fa=wv, ks=j) at (wv*2+j)*1024
  auto stageA2 = [&](int buf, int ss) {
#pragma unroll
    for (int j = 0; j < 2; ++j) {
      __builtin_amdgcn_global_load_lds(
          (const __attribute__((address_space(1))) uint32_t*)(
              gA + ss * BKB + j * 32),
          (__attribute__((address_space(3))) uint32_t*)(
              &lds[buf][(wv * 2 + j) * 1024 + l * 16]),
          16, 0, 0);
    }
  };

  // load 4 B frags (2 n x 2 ks) for step ss: b[n*2+ks]
  auto loadB = [&](int32x4 (&b)[4], int ss) {
    b[0] = *(const int32x4*)(gB0 + ((size_t)(ss * 2 + 0) << 10));
    b[1] = *(const int32x4*)(gB0 + ((size_t)(ss * 2 + 1) << 10));
    b[2] = *(const int32x4*)(gB1 + ((size_t)(ss * 2 + 0) << 10));
    b[3] = *(const int32x4*)(gB1 + ((size_t)(ss * 2 + 1) << 10));
  };

#define PHASE_OPEN()                                    \
  __builtin_amdgcn_s_barrier();                         \
  asm volatile("s_waitcnt lgkmcnt(0)" ::: "memory");    \
  __builtin_amdgcn_sched_barrier(0);                    \
  __builtin_amdgcn_s_setprio(1);

#define PHASE_CLOSE()                                   \
  __builtin_amdgcn_s_setprio(0);

  const int nsteps = K_DIM / BKB;  // 64

  // one step (2 phases); a-frags reloaded per phase, bCur indexed statically
  auto do_step = [&](int s, int32x4 (&bCur)[4], int32x4 (&bNext)[4]) {
    const int buf = s & 1;
    const uint8_t* aB = &lds[buf][wm * 8192 + l * 16];

    // ---- Phase 1: ks0, all m ----
    int32x4 a[4];
#pragma unroll
    for (int m = 0; m < 4; ++m)
      a[m] = *(const int32x4*)(aB + m * 2048 + 0 * 1024);
    stageA2(buf ^ 1, (s + 1) & 63);
    PHASE_OPEN()
#pragma unroll
    for (int m = 0; m < 4; ++m) {
      acc[m][0] = __builtin_amdgcn_mfma_i32_32x32x32_i8(a[m], bCur[0],
                                                        acc[m][0], 0, 0, 0);
      acc[m][1] = __builtin_amdgcn_mfma_i32_32x32x32_i8(a[m], bCur[2],
                                                        acc[m][1], 0, 0, 0);
    }
    PHASE_CLOSE()
    __builtin_amdgcn_s_barrier();

    // ---- Phase 2: ks1, all m ----
    int32x4 c[4];
#pragma unroll
    for (int m = 0; m < 4; ++m)
      c[m] = *(const int32x4*)(aB + m * 2048 + 1 * 1024);
    loadB(bNext, (s + 1) & 63);
    PHASE_OPEN()
#pragma unroll
    for (int m = 0; m < 4; ++m) {
      acc[m][0] = __builtin_amdgcn_mfma_i32_32x32x32_i8(c[m], bCur[1],
                                                        acc[m][0], 0, 0, 0);
      acc[m][1] = __builtin_amdgcn_mfma_i32_32x32x32_i8(c[m], bCur[3],
                                                        acc[m][1], 0, 0, 0);
    }
    PHASE_CLOSE()
    // retire exactly stageA(s+1) x2; loadB(s+1) x4 stay in flight
    asm volatile("s_waitcnt vmcnt(4)" ::: "memory");
    __builtin_amdgcn_s_barrier();
  };

  // prologue: A(0)->buf0, B(0)->bX; vmcnt(4) retires A(0)
  int32x4 bX[4], bY[4];
  stageA2(0, 0);
  asm volatile("" ::: "memory");  // pin: A-stages before B-loads
  loadB(bX, 0);
  asm volatile("s_waitcnt vmcnt(4)" ::: "memory");
  __builtin_amdgcn_s_barrier();

  for (int s = 0; s < nsteps; s += 2) {
    do_step(s, bX, bY);      // consumes bX, prefetches into bY
    do_step(s + 1, bY, bX);  // consumes bY, prefetches into bX
  }
  asm volatile("s_waitcnt vmcnt(0)" ::: "memory");  // drain dead prefetches

#undef PHASE_OPEN
#undef PHASE_CLOSE

  // epilogue: dequant + fp16-round, write f32
  const int colbase = tn + wn * 64;
  const int rowbase = tm + wm * 128 + 4 * (l >> 5);
#pragma unroll
  for (int m = 0; m < 4; ++m) {
#pragma unroll
    for (int n = 0; n < 2; ++n) {
      const int col = colbase + n * 32 + (l & 31);
      const float wsc = wscale[col];
#pragma unroll
      for (int j = 0; j < 16; ++j) {
        const int row = rowbase + m * 32 + (j & 3) + 8 * (j >> 2);
        const float val = (float)acc[m][n][j] * (xs[row] * wsc);
        out[(size_t)row * N_OUT + col] = __half2float(__float2half(val));
      }
    }
  }
}

extern "C" void kernel_launch(void* const* d_in, const int* in_sizes, int n_in,
                              void* d_out, int out_size, void* d_ws, size_t ws_size,
                              hipStream_t stream) {
  const float* x = (const float*)d_in[0];    // fp16 values as f32
  const int* w = (const int*)d_in[1];        // int4-range values as i32
  const float* wsc = (const float*)d_in[2];  // fp16 values as f32
  float* out = (float*)d_out;

  const int M = in_sizes[0] / K_DIM;  // 8192 tokens

  uint8_t* ws = (uint8_t*)d_ws;
  int8_t* xq = (int8_t*)ws;                              // M*K bytes
  uint8_t* wqf = ws + (size_t)M * K_DIM;                 // N*K bytes (frag-major)
  float* xs = (float*)(ws + (size_t)M * K_DIM + (size_t)N_OUT * K_DIM);

  quant_x<<<M, 256, 0, stream>>>(x, xq, xs);
  pack_w<<<(N_OUT * K_DIM / 16) / 256, 256, 0, stream>>>(w, (uint32_t*)wqf);
  gemm_w4a4<<<(M / BM) * (N_OUT / BN), 512, 0, stream>>>(
      xq, wqf, xs, wsc, out, M);
}

// Round 17
// 217.825 us; speedup vs baseline: 1.0582x; 1.0582x over previous
//
#include <hip/hip_runtime.h>
#include <hip/hip_fp16.h>
#include <stdint.h>

#define K_DIM 4096
#define N_OUT 4096
#define BM 256
#define BN 128
#define BKB 64  // K-bytes per step = 2 MFMA K-slices

typedef __attribute__((ext_vector_type(4))) int int32x4;
typedef __attribute__((ext_vector_type(16))) int int32x16;

// ---------------- per-token int4 activation quantization ----------------
// x_scale = max(x_max/7, fp16(1e-5)); x_q = clip(rint(x/x_scale), -8, 7).
// All f32; no intermediate fp16 rounding (matches harness np reference).
__global__ __launch_bounds__(256) void quant_x(const float* __restrict__ x,
                                               int8_t* __restrict__ xq,
                                               float* __restrict__ xs) {
  const int row = blockIdx.x;
  const int t = threadIdx.x;
  const float4* xr = (const float4*)(x + (size_t)row * K_DIM);
  float4 v[4];
  float m = 0.f;
#pragma unroll
  for (int i = 0; i < 4; ++i) {
    v[i] = xr[t * 4 + i];
    m = fmaxf(m, fmaxf(fmaxf(fabsf(v[i].x), fabsf(v[i].y)),
                       fmaxf(fabsf(v[i].z), fabsf(v[i].w))));
  }
#pragma unroll
  for (int off = 32; off > 0; off >>= 1) m = fmaxf(m, __shfl_xor(m, off));
  __shared__ float wmax[4];
  if ((t & 63) == 0) wmax[t >> 6] = m;
  __syncthreads();
  m = fmaxf(fmaxf(wmax[0], wmax[1]), fmaxf(wmax[2], wmax[3]));

  const float eps = 1.0013580322265625e-05f;  // fp16(1e-5) as f32
  const float xscale = fmaxf(m / 7.0f, eps);
  if (t == 0) xs[row] = xscale;

  uint32_t p[4];
#pragma unroll
  for (int g = 0; g < 4; ++g) {
    const float* fv = (const float*)&v[g];
    uint32_t w = 0;
#pragma unroll
    for (int j = 0; j < 4; ++j) {
      float r = rintf(fv[j] / xscale);
      r = fminf(fmaxf(r, -8.f), 7.f);
      w |= ((uint32_t)(uint8_t)(int8_t)(int)r) << (8 * j);
    }
    p[g] = w;
  }
  *(uint4*)(xq + (size_t)row * K_DIM + t * 16) = *(uint4*)p;
}

// ---------------- weight pack: int32 -> int8, FRAGMENT-MAJOR ----------------
// block b = nfrag*128 + kslice; each block 1024B in MFMA lane order.
__global__ __launch_bounds__(256) void pack_w(const int* __restrict__ w,
                                              uint32_t* __restrict__ wqf) {
  const int c = blockIdx.x * 256 + threadIdx.x;  // one thread per 16B chunk
  const int blk = c >> 6;
  const int l = c & 63;
  const int row = ((blk >> 7) << 5) + (l & 31);
  const int k = ((blk & 127) << 5) + ((l >> 5) << 4);
  const int4* src = (const int4*)(w + (size_t)row * K_DIM + k);  // 16 ints
  uint32_t p[4];
#pragma unroll
  for (int g = 0; g < 4; ++g) {
    const int4 v = src[g];
    p[g] = (uint32_t)(v.x & 255) | ((uint32_t)(v.y & 255) << 8) |
           ((uint32_t)(v.z & 255) << 16) | ((uint32_t)(v.w & 255) << 24);
  }
  *(uint4*)(wqf + (size_t)c * 4) = *(uint4*)p;
}

// ---------------- i8 GEMM: out = dequant(xq . wq^T) ----------------
// r17 = r14's phase discipline (validated +20%) re-tiled for block-level
// drift: 256x128 tile, 4 waves (2m x 2n, 256 thr), wave tile 128x64 (same
// acc = 128 AGPR), 3-deep LDS = 72KB -> TWO independent blocks per CU
// (same 2 waves/SIMD, but from different blocks -> one block's MFMA cluster
// covers the other's ds_read phase; r14's 96KB forced 1 block/CU lockstep).
// Per step: P1 {6 ds_reads (a ks0, b ks0) | stageA(s+2) x4 | OPEN | 8 MFMA |
//               bar}
//           P2 {6 ds_reads (ks1) | stageB(s+2) x2 | OPEN | 8 MFMA |
//               vmcnt(6) | bar}
// vmcnt ledger/wave: issued per step = [A(s+2)x4, B(s+2)x2]; at end of step
// outstanding = 12 (steps s+1, s+2); vmcnt(6) retires exactly step-(s+1)'s 6
// (2-step lead, never 0 in loop). WAR: stage(s+2) targets buf[(s-1)%3],
// whose reads finished 2 barriers ago.
__global__ __launch_bounds__(256, 2) void gemm_w4a4(
    const int8_t* __restrict__ xq, const uint8_t* __restrict__ wqf,
    const float* __restrict__ xs, const float* __restrict__ wscale,
    float* __restrict__ out, int M) {
  __shared__ uint8_t lds[3][24576];  // [buf][A: 16 blk x 1KB | B: 8 blk x 1KB]

  // Swizzle (r8 family): A-panels XCD-exclusive (4 x 1MB, L2-resident).
  const int bid = blockIdx.x;
  const int xcd = bid & 7;
  const int i_loc = bid >> 3;            // 0..127
  const int mt = xcd * 4 + (i_loc & 3);  // 0..31, XCD-exclusive
  const int nt = i_loc >> 2;             // 0..31
  const int tm = mt * BM;
  const int tn = nt * BN;

  const int t = threadIdx.x;  // 0..255
  const int l = t & 63;
  const int wv = t >> 6;      // 0..3
  const int wm = wv >> 1;     // 0..1
  const int wn = wv & 1;      // 0..1

  // A staging source (validated lane map): row (l&31), k-chunk (l>>5)*16
  const uint8_t* gA = (const uint8_t*)xq + (size_t)(tm + (l & 31)) * K_DIM +
                      ((l >> 5) << 4);
  // B staging source: frag-major wqf
  const uint8_t* gB = wqf + (size_t)(nt * 4) * 131072 + (size_t)l * 16;

  int32x16 acc[4][2] = {};

  // stage A of step ss into buf: blocks bIdx = q*4+wv (fa=bIdx>>1, ks=bIdx&1)
  // LDS dest = bIdx*1024 + l*16 = q*4096 + t*16 (linear in t, as required).
  auto stageA4 = [&](int buf, int ss) {
#pragma unroll
    for (int q = 0; q < 4; ++q) {
      const int bIdx = q * 4 + wv;
      __builtin_amdgcn_global_load_lds(
          (const __attribute__((address_space(1))) uint32_t*)(
              gA + (size_t)((bIdx >> 1) * 32) * K_DIM + (bIdx & 1) * 32 +
              ss * BKB),
          (__attribute__((address_space(3))) uint32_t*)(
              &lds[buf][q * 4096 + t * 16]),
          16, 0, 0);
    }
  };
  // stage B of step ss into buf: blocks bIdx = q*4+wv (nf=bIdx>>1, ks=bIdx&1)
  auto stageB2 = [&](int buf, int ss) {
#pragma unroll
    for (int q = 0; q < 2; ++q) {
      const int bIdx = q * 4 + wv;
      __builtin_amdgcn_global_load_lds(
          (const __attribute__((address_space(1))) uint32_t*)(
              gB + (size_t)(bIdx >> 1) * 131072 +
              ((size_t)(ss * 2 + (bIdx & 1)) << 10)),
          (__attribute__((address_space(3))) uint32_t*)(
              &lds[buf][16384 + q * 4096 + t * 16]),
          16, 0, 0);
    }
  };

#define PHASE_OPEN()                                    \
  __builtin_amdgcn_s_barrier();                         \
  asm volatile("s_waitcnt lgkmcnt(0)" ::: "memory");    \
  __builtin_amdgcn_sched_barrier(0);                    \
  __builtin_amdgcn_s_setprio(1);

#define PHASE_CLOSE()                                   \
  __builtin_amdgcn_s_setprio(0);

  const int nsteps = K_DIM / BKB;  // 64

  // prologue: stage steps 0 (buf0) and 1 (buf1); retire step-0's 6 glds
  stageA4(0, 0);
  stageB2(0, 0);
  stageA4(1, 1);
  stageB2(1, 1);
  asm volatile("s_waitcnt vmcnt(6)" ::: "memory");
  __builtin_amdgcn_s_barrier();

  for (int s = 0; s < nsteps; ++s) {
    const int buf = s % 3;
    const int sbuf = (s + 2) % 3;
    const int ss = (s + 2) & 63;  // wrapped (dead-but-harmless at tail)
    const uint8_t* aB = &lds[buf][wm * 8192 + l * 16];
    const uint8_t* bB = &lds[buf][16384 + wn * 4096 + l * 16];

    // ---- Phase 1: ks0 ----
    int32x4 a[4], b0[2];
#pragma unroll
    for (int m = 0; m < 4; ++m)
      a[m] = *(const int32x4*)(aB + m * 2048 + 0 * 1024);
#pragma unroll
    for (int n = 0; n < 2; ++n)
      b0[n] = *(const int32x4*)(bB + n * 2048 + 0 * 1024);
    stageA4(sbuf, ss);
    PHASE_OPEN()
#pragma unroll
    for (int m = 0; m < 4; ++m) {
      acc[m][0] = __builtin_amdgcn_mfma_i32_32x32x32_i8(a[m], b0[0],
                                                        acc[m][0], 0, 0, 0);
      acc[m][1] = __builtin_amdgcn_mfma_i32_32x32x32_i8(a[m], b0[1],
                                                        acc[m][1], 0, 0, 0);
    }
    PHASE_CLOSE()
    __builtin_amdgcn_s_barrier();

    // ---- Phase 2: ks1 ----
    int32x4 c[4], b1[2];
#pragma unroll
    for (int m = 0; m < 4; ++m)
      c[m] = *(const int32x4*)(aB + m * 2048 + 1 * 1024);
#pragma unroll
    for (int n = 0; n < 2; ++n)
      b1[n] = *(const int32x4*)(bB + n * 2048 + 1 * 1024);
    stageB2(sbuf, ss);
    PHASE_OPEN()
#pragma unroll
    for (int m = 0; m < 4; ++m) {
      acc[m][0] = __builtin_amdgcn_mfma_i32_32x32x32_i8(c[m], b1[0],
                                                        acc[m][0], 0, 0, 0);
      acc[m][1] = __builtin_amdgcn_mfma_i32_32x32x32_i8(c[m], b1[1],
                                                        acc[m][1], 0, 0, 0);
    }
    PHASE_CLOSE()
    // retire step-(s+1)'s 6 glds; step-(s+2)'s 6 stay in flight
    asm volatile("s_waitcnt vmcnt(6)" ::: "memory");
    __builtin_amdgcn_s_barrier();
  }
  asm volatile("s_waitcnt vmcnt(0)" ::: "memory");  // drain dead prefetches

#undef PHASE_OPEN
#undef PHASE_CLOSE

  // epilogue: dequant + fp16-round, write f32
  const int colbase = tn + wn * 64;
  const int rowbase = tm + wm * 128 + 4 * (l >> 5);
#pragma unroll
  for (int m = 0; m < 4; ++m) {
#pragma unroll
    for (int n = 0; n < 2; ++n) {
      const int col = colbase + n * 32 + (l & 31);
      const float wsc = wscale[col];
#pragma unroll
      for (int j = 0; j < 16; ++j) {
        const int row = rowbase + m * 32 + (j & 3) + 8 * (j >> 2);
        const float val = (float)acc[m][n][j] * (xs[row] * wsc);
        out[(size_t)row * N_OUT + col] = __half2float(__float2half(val));
      }
    }
  }
}

extern "C" void kernel_launch(void* const* d_in, const int* in_sizes, int n_in,
                              void* d_out, int out_size, void* d_ws, size_t ws_size,
                              hipStream_t stream) {
  const float* x = (const float*)d_in[0];    // fp16 values as f32
  const int* w = (const int*)d_in[1];        // int4-range values as i32
  const float* wsc = (const float*)d_in[2];  // fp16 values as f32
  float* out = (float*)d_out;

  const int M = in_sizes[0] / K_DIM;  // 8192 tokens

  uint8_t* ws = (uint8_t*)d_ws;
  int8_t* xq = (int8_t*)ws;                              // M*K bytes
  uint8_t* wqf = ws + (size_t)M * K_DIM;                 // N*K bytes (frag-major)
  float* xs = (float*)(ws + (size_t)M * K_DIM + (size_t)N_OUT * K_DIM);

  quant_x<<<M, 256, 0, stream>>>(x, xq, xs);
  pack_w<<<(N_OUT * K_DIM / 16) / 256, 256, 0, stream>>>(w, (uint32_t*)wqf);
  gemm_w4a4<<<(M / BM) * (N_OUT / BN), 256, 0, stream>>>(
      xq, wqf, xs, wsc, out, M);
}

// Round 19
// 201.540 us; speedup vs baseline: 1.1437x; 1.0808x over previous
//
#include <hip/hip_runtime.h>
#include <hip/hip_fp16.h>
#include <stdint.h>

#define K_DIM 4096
#define N_OUT 4096
#define BM 256
#define BN 256
#define BKB 64  // K-bytes per step = 2 MFMA K-slices

typedef __attribute__((ext_vector_type(4))) int int32x4;
typedef __attribute__((ext_vector_type(16))) int int32x16;

// ---------------- per-token int4 activation quantization ----------------
// x_scale = max(x_max/7, fp16(1e-5)); x_q = clip(rint(x/x_scale), -8, 7).
// All f32; no intermediate fp16 rounding (matches harness np reference).
__global__ __launch_bounds__(256) void quant_x(const float* __restrict__ x,
                                               int8_t* __restrict__ xq,
                                               float* __restrict__ xs) {
  const int row = blockIdx.x;
  const int t = threadIdx.x;
  const float4* xr = (const float4*)(x + (size_t)row * K_DIM);
  float4 v[4];
  float m = 0.f;
#pragma unroll
  for (int i = 0; i < 4; ++i) {
    v[i] = xr[t * 4 + i];
    m = fmaxf(m, fmaxf(fmaxf(fabsf(v[i].x), fabsf(v[i].y)),
                       fmaxf(fabsf(v[i].z), fabsf(v[i].w))));
  }
#pragma unroll
  for (int off = 32; off > 0; off >>= 1) m = fmaxf(m, __shfl_xor(m, off));
  __shared__ float wmax[4];
  if ((t & 63) == 0) wmax[t >> 6] = m;
  __syncthreads();
  m = fmaxf(fmaxf(wmax[0], wmax[1]), fmaxf(wmax[2], wmax[3]));

  const float eps = 1.0013580322265625e-05f;  // fp16(1e-5) as f32
  const float xscale = fmaxf(m / 7.0f, eps);
  if (t == 0) xs[row] = xscale;

  uint32_t p[4];
#pragma unroll
  for (int g = 0; g < 4; ++g) {
    const float* fv = (const float*)&v[g];
    uint32_t w = 0;
#pragma unroll
    for (int j = 0; j < 4; ++j) {
      float r = rintf(fv[j] / xscale);
      r = fminf(fmaxf(r, -8.f), 7.f);
      w |= ((uint32_t)(uint8_t)(int8_t)(int)r) << (8 * j);
    }
    p[g] = w;
  }
  *(uint4*)(xq + (size_t)row * K_DIM + t * 16) = *(uint4*)p;
}

// ---------------- weight pack: int32 -> int8, FRAGMENT-MAJOR ----------------
// block b = nfrag*128 + kslice; each block 1024B in MFMA lane order.
__global__ __launch_bounds__(256) void pack_w(const int* __restrict__ w,
                                              uint32_t* __restrict__ wqf) {
  const int c = blockIdx.x * 256 + threadIdx.x;  // one thread per 16B chunk
  const int blk = c >> 6;
  const int l = c & 63;
  const int row = ((blk >> 7) << 5) + (l & 31);
  const int k = ((blk & 127) << 5) + ((l >> 5) << 4);
  const int4* src = (const int4*)(w + (size_t)row * K_DIM + k);  // 16 ints
  uint32_t p[4];
#pragma unroll
  for (int g = 0; g < 4; ++g) {
    const int4 v = src[g];
    p[g] = (uint32_t)(v.x & 255) | ((uint32_t)(v.y & 255) << 8) |
           ((uint32_t)(v.z & 255) << 16) | ((uint32_t)(v.w & 255) << 24);
  }
  *(uint4*)(wqf + (size_t)c * 4) = *(uint4*)p;
}

// ---------------- i8 GEMM: out = dequant(xq . wq^T) ----------------
// r19 = r18's register-level software pipeline with the cross-barrier
// prefetch race FIXED by pipeline depth:
//  - LDS 4-deep (4 x 32KB = 128KB), staged 3 AHEAD (stage(s+3) per step).
//  - End-of-step vmcnt(6) retires stage(s+2) (outstanding 12 -> 6).
//  - INVARIANT: after the barrier closing step s-1, buffers s AND s+1 are
//    block-wide ready. Hence the end-of-step ks0 prefetch from buf (s+1)%4
//    is safe: its readiness came from the PREVIOUS barrier (r18 read a
//    buffer only one barrier old -> raced other waves' staging).
//  - Per step: {6 ds_read ks1 | 6 staging glds | lgkmcnt(6)+schedbar ->
//    8 MFMA ks0 | lgkmcnt(0)+schedbar -> 8 MFMA ks1 | vmcnt(6)+schedbar |
//    prefetch ks0(s+1) | s_barrier}. One barrier/step; never vmcnt(0).
//  - WAR: stage(s+3) targets buf (s-1)%4 whose reads finished before the
//    previous barrier. Tail wrap-writes touch only never-again-read buffers.
__global__ __launch_bounds__(512, 2) void gemm_w4a4(
    const int8_t* __restrict__ xq, const uint8_t* __restrict__ wqf,
    const float* __restrict__ xs, const float* __restrict__ wscale,
    float* __restrict__ out, int M) {
  __shared__ uint8_t lds[4][32768];  // [buf][A: 16 blk x 1KB | B: 16 blk x 1KB]

  // Swizzle (validated r8): A-panels XCD-exclusive, L2-resident.
  const int bid = blockIdx.x;
  const int xcd = bid & 7;
  const int i_loc = bid >> 3;            // 0..63
  const int mt = xcd * 4 + (i_loc & 3);  // 0..31, XCD-exclusive
  const int nt = i_loc >> 2;             // 0..15
  const int tm = mt * BM;
  const int tn = nt * BN;

  const int t = threadIdx.x;  // 0..511
  const int l = t & 63;
  const int wv = t >> 6;      // 0..7
  const int wm = wv >> 2;     // 0..1
  const int wn = wv & 3;      // 0..3

  // A staging source (validated lane map): row (l&31), k-chunk (l>>5)*16
  const uint8_t* gA = (const uint8_t*)xq +
                      (size_t)(tm + wv * 32 + (l & 31)) * K_DIM +
                      ((l >> 5) << 4);
  // B staging source: frag-major wqf, wave wv stages nfrag (nt*8+wv)
  const uint8_t* gB = wqf + (size_t)(nt * 8 + wv) * 131072 + (size_t)l * 16;

  int32x16 acc[4][2] = {};

  // stage A of step ss into buf: blocks (fa=wv, ks=j) at (wv*2+j)*1024
  auto stageA2 = [&](int buf, int ss) {
#pragma unroll
    for (int j = 0; j < 2; ++j) {
      __builtin_amdgcn_global_load_lds(
          (const __attribute__((address_space(1))) uint32_t*)(
              gA + ss * BKB + j * 32),
          (__attribute__((address_space(3))) uint32_t*)(
              &lds[buf][(wv * 2 + j) * 1024 + l * 16]),
          16, 0, 0);
    }
  };
  // stage B of step ss into buf: kslices (ss*2+j) -> 16384 + (wv*2+j)*1024
  auto stageB2 = [&](int buf, int ss) {
#pragma unroll
    for (int j = 0; j < 2; ++j) {
      __builtin_amdgcn_global_load_lds(
          (const __attribute__((address_space(1))) uint32_t*)(
              gB + ((size_t)(ss * 2 + j) << 10)),
          (__attribute__((address_space(3))) uint32_t*)(
              &lds[buf][16384 + (wv * 2 + j) * 1024 + l * 16]),
          16, 0, 0);
    }
  };

  const int nsteps = K_DIM / BKB;  // 64

  // prologue: stage steps 0,1,2 (bufs 0,1,2) = 18 glds; vmcnt(6) retires
  // stage(0)+stage(1) -> after the barrier, buffers 0 AND 1 are block-ready.
  stageA2(0, 0);
  stageB2(0, 0);
  stageA2(1, 1);
  stageB2(1, 1);
  stageA2(2, 2);
  stageB2(2, 2);
  asm volatile("s_waitcnt vmcnt(6)" ::: "memory");
  __builtin_amdgcn_s_barrier();

  int32x4 a0[4], b0[2], a1[4], b1[2];
  {
    const uint8_t* aB = &lds[0][wm * 8192 + l * 16];
    const uint8_t* bB = &lds[0][16384 + wn * 4096 + l * 16];
#pragma unroll
    for (int m = 0; m < 4; ++m) a0[m] = *(const int32x4*)(aB + m * 2048);
#pragma unroll
    for (int n = 0; n < 2; ++n) b0[n] = *(const int32x4*)(bB + n * 2048);
  }

  for (int s = 0; s < nsteps; ++s) {
    const int buf = s & 3;
    const int sbuf = (s + 3) & 3;
    const int ss = (s + 3) & 63;  // wrapped; tail writes hit dead buffers only
    const uint8_t* aB = &lds[buf][wm * 8192 + l * 16];
    const uint8_t* bB = &lds[buf][16384 + wn * 4096 + l * 16];

    // issue ks1 reads (6) — land under MFMA cluster 1
#pragma unroll
    for (int m = 0; m < 4; ++m)
      a1[m] = *(const int32x4*)(aB + m * 2048 + 1024);
#pragma unroll
    for (int n = 0; n < 2; ++n)
      b1[n] = *(const int32x4*)(bB + n * 2048 + 1024);
    // staging for step s+3 (6 glds)
    stageA2(sbuf, ss);
    stageB2(sbuf, ss);

    // cluster 1 (ks0): carried a0/b0 retired by lgkmcnt(6) (ks1's 6 remain)
    asm volatile("s_waitcnt lgkmcnt(6)" ::: "memory");
    __builtin_amdgcn_sched_barrier(0);
    __builtin_amdgcn_s_setprio(1);
#pragma unroll
    for (int m = 0; m < 4; ++m) {
      acc[m][0] = __builtin_amdgcn_mfma_i32_32x32x32_i8(a0[m], b0[0],
                                                        acc[m][0], 0, 0, 0);
      acc[m][1] = __builtin_amdgcn_mfma_i32_32x32x32_i8(a0[m], b0[1],
                                                        acc[m][1], 0, 0, 0);
    }
    __builtin_amdgcn_s_setprio(0);

    // cluster 2 (ks1)
    asm volatile("s_waitcnt lgkmcnt(0)" ::: "memory");
    __builtin_amdgcn_sched_barrier(0);
    __builtin_amdgcn_s_setprio(1);
#pragma unroll
    for (int m = 0; m < 4; ++m) {
      acc[m][0] = __builtin_amdgcn_mfma_i32_32x32x32_i8(a1[m], b1[0],
                                                        acc[m][0], 0, 0, 0);
      acc[m][1] = __builtin_amdgcn_mfma_i32_32x32x32_i8(a1[m], b1[1],
                                                        acc[m][1], 0, 0, 0);
    }
    __builtin_amdgcn_s_setprio(0);

    // retire stage(s+2); stage(s+3) stays in flight (never vmcnt(0))
    asm volatile("s_waitcnt vmcnt(6)" ::: "memory");
    __builtin_amdgcn_sched_barrier(0);

    // cross-barrier prefetch of next step's ks0 from buf (s+1)&3 — SAFE:
    // buffer s+1 became block-wide ready at the barrier closing step s-1.
    const uint8_t* aN = &lds[(s + 1) & 3][wm * 8192 + l * 16];
    const uint8_t* bN = &lds[(s + 1) & 3][16384 + wn * 4096 + l * 16];
#pragma unroll
    for (int m = 0; m < 4; ++m) a0[m] = *(const int32x4*)(aN + m * 2048);
#pragma unroll
    for (int n = 0; n < 2; ++n) b0[n] = *(const int32x4*)(bN + n * 2048);

    __builtin_amdgcn_s_barrier();
  }
  asm volatile("s_waitcnt vmcnt(0) lgkmcnt(0)" ::: "memory");  // drain tail

  // epilogue: dequant + fp16-round, write f32
  const int colbase = tn + wn * 64;
  const int rowbase = tm + wm * 128 + 4 * (l >> 5);
#pragma unroll
  for (int m = 0; m < 4; ++m) {
#pragma unroll
    for (int n = 0; n < 2; ++n) {
      const int col = colbase + n * 32 + (l & 31);
      const float wsc = wscale[col];
#pragma unroll
      for (int j = 0; j < 16; ++j) {
        const int row = rowbase + m * 32 + (j & 3) + 8 * (j >> 2);
        const float val = (float)acc[m][n][j] * (xs[row] * wsc);
        out[(size_t)row * N_OUT + col] = __half2float(__float2half(val));
      }
    }
  }
}

extern "C" void kernel_launch(void* const* d_in, const int* in_sizes, int n_in,
                              void* d_out, int out_size, void* d_ws, size_t ws_size,
                              hipStream_t stream) {
  const float* x = (const float*)d_in[0];    // fp16 values as f32
  const int* w = (const int*)d_in[1];        // int4-range values as i32
  const float* wsc = (const float*)d_in[2];  // fp16 values as f32
  float* out = (float*)d_out;

  const int M = in_sizes[0] / K_DIM;  // 8192 tokens

  uint8_t* ws = (uint8_t*)d_ws;
  int8_t* xq = (int8_t*)ws;                              // M*K bytes
  uint8_t* wqf = ws + (size_t)M * K_DIM;                 // N*K bytes (frag-major)
  float* xs = (float*)(ws + (size_t)M * K_DIM + (size_t)N_OUT * K_DIM);

  quant_x<<<M, 256, 0, stream>>>(x, xq, xs);
  pack_w<<<(N_OUT * K_DIM / 16) / 256, 256, 0, stream>>>(w, (uint32_t*)wqf);
  gemm_w4a4<<<(M / BM) * (N_OUT / BN), 512, 0, stream>>>(
      xq, wqf, xs, wsc, out, M);
}

// Round 20
// 187.983 us; speedup vs baseline: 1.2262x; 1.0721x over previous
//
#include <hip/hip_runtime.h>
#include <hip/hip_fp16.h>
#include <stdint.h>

#define K_DIM 4096
#define N_OUT 4096
#define BM 256
#define BN 256
#define BKB 64  // K-bytes per step = 2 MFMA K-slices

typedef __attribute__((ext_vector_type(4))) int int32x4;
typedef __attribute__((ext_vector_type(16))) int int32x16;

// ------------- fused prologue: per-token quant (blocks < M) + weight pack ---
// quant: x_scale = max(x_max/7, fp16(1e-5)); x_q = clip(rint(x/x_scale),-8,7)
//        (all f32, no intermediate fp16 rounding — matches np reference).
// pack:  int32 -> int8 FRAGMENT-MAJOR wqf: block b = nfrag*128 + kslice,
//        each block 1024B in MFMA lane order.
__global__ __launch_bounds__(256) void quant_pack(
    const float* __restrict__ x, const int* __restrict__ w,
    int8_t* __restrict__ xq, float* __restrict__ xs,
    uint32_t* __restrict__ wqf, int M) {
  __shared__ float wmax[4];
  const int t = threadIdx.x;
  if ((int)blockIdx.x < M) {
    const int row = blockIdx.x;
    const float4* xr = (const float4*)(x + (size_t)row * K_DIM);
    float4 v[4];
    float m = 0.f;
#pragma unroll
    for (int i = 0; i < 4; ++i) {
      v[i] = xr[t * 4 + i];
      m = fmaxf(m, fmaxf(fmaxf(fabsf(v[i].x), fabsf(v[i].y)),
                         fmaxf(fabsf(v[i].z), fabsf(v[i].w))));
    }
#pragma unroll
    for (int off = 32; off > 0; off >>= 1) m = fmaxf(m, __shfl_xor(m, off));
    if ((t & 63) == 0) wmax[t >> 6] = m;
    __syncthreads();
    m = fmaxf(fmaxf(wmax[0], wmax[1]), fmaxf(wmax[2], wmax[3]));

    const float eps = 1.0013580322265625e-05f;  // fp16(1e-5) as f32
    const float xscale = fmaxf(m / 7.0f, eps);
    if (t == 0) xs[row] = xscale;

    uint32_t p[4];
#pragma unroll
    for (int g = 0; g < 4; ++g) {
      const float* fv = (const float*)&v[g];
      uint32_t wd = 0;
#pragma unroll
      for (int j = 0; j < 4; ++j) {
        float r = rintf(fv[j] / xscale);
        r = fminf(fmaxf(r, -8.f), 7.f);
        wd |= ((uint32_t)(uint8_t)(int8_t)(int)r) << (8 * j);
      }
      p[g] = wd;
    }
    *(uint4*)(xq + (size_t)row * K_DIM + t * 16) = *(uint4*)p;
  } else {
    const int c = (blockIdx.x - M) * 256 + t;  // one thread per 16B chunk
    const int blk = c >> 6;
    const int l = c & 63;
    const int row = ((blk >> 7) << 5) + (l & 31);
    const int k = ((blk & 127) << 5) + ((l >> 5) << 4);
    const int4* src = (const int4*)(w + (size_t)row * K_DIM + k);  // 16 ints
    uint32_t p[4];
#pragma unroll
    for (int g = 0; g < 4; ++g) {
      const int4 v = src[g];
      p[g] = (uint32_t)(v.x & 255) | ((uint32_t)(v.y & 255) << 8) |
             ((uint32_t)(v.z & 255) << 16) | ((uint32_t)(v.w & 255) << 24);
    }
    *(uint4*)(wqf + (size_t)c * 4) = *(uint4*)p;
  }
}

// ---------------- i8 GEMM: out = dequant(xq . wq^T) ----------------
// r20 = r14 (best validated: 145us, MfmaUtil 43.5%) with the buffer rotation
// made COMPILE-TIME: LDS 4-deep (4x32KB = 128KB, still 1 block/CU), K-loop
// unrolled x4 so buf = s&3 = u and sbuf = (u+2)&3 are constants — removes
// the runtime s%3 magic-multiply + pointer math that sat between each
// barrier and its ds_read issue (VALUBusy 16% -> target ~10%).
// Phase semantics bit-identical to r14:
//  P1 {8 ds_read (a m0,m1 x ks0,ks1; b n0,n1 x ks0,ks1) | stageA2(s+2) |
//      BARRIER | lgkmcnt(0)+sched_barrier | setprio+8 MFMA+setprio | BARRIER}
//  P2 {4 ds_read (a m2,m3) | stageB2(s+2) | BARRIER | lgkmcnt(0)+sched_bar |
//      setprio+8 MFMA+setprio | vmcnt(4) | BARRIER}
// vmcnt(4) retires step-(s+1)'s 4 glds; step-(s+2)'s stay in flight (never 0
// in loop). WAR: stage(s+2) targets buf (s+2)&3, last read at step s-2,
// 4 barriers ago. Tail wrap-writes touch only never-again-read buffers.
__global__ __launch_bounds__(512, 2) void gemm_w4a4(
    const int8_t* __restrict__ xq, const uint8_t* __restrict__ wqf,
    const float* __restrict__ xs, const float* __restrict__ wscale,
    float* __restrict__ out, int M) {
  __shared__ uint8_t lds[4][32768];  // [buf][A: 16 blk x 1KB | B: 16 blk x 1KB]

  // Swizzle (validated r8): A-panels XCD-exclusive, L2-resident.
  const int bid = blockIdx.x;
  const int xcd = bid & 7;
  const int i_loc = bid >> 3;            // 0..63
  const int mt = xcd * 4 + (i_loc & 3);  // 0..31, XCD-exclusive
  const int nt = i_loc >> 2;             // 0..15
  const int tm = mt * BM;
  const int tn = nt * BN;

  const int t = threadIdx.x;  // 0..511
  const int l = t & 63;
  const int wv = t >> 6;      // 0..7
  const int wm = wv >> 2;     // 0..1
  const int wn = wv & 3;      // 0..3

  // A staging source (validated lane map): row (l&31), k-chunk (l>>5)*16
  const uint8_t* gA = (const uint8_t*)xq +
                      (size_t)(tm + wv * 32 + (l & 31)) * K_DIM +
                      ((l >> 5) << 4);
  // B staging source: frag-major wqf, wave wv stages nfrag (nt*8+wv)
  const uint8_t* gB = wqf + (size_t)(nt * 8 + wv) * 131072 + (size_t)l * 16;

  int32x16 acc[4][2] = {};

  // stage A of step ss into buf: blocks (fa=wv, ks=j) at (wv*2+j)*1024
  auto stageA2 = [&](int buf, int ss) {
#pragma unroll
    for (int j = 0; j < 2; ++j) {
      __builtin_amdgcn_global_load_lds(
          (const __attribute__((address_space(1))) uint32_t*)(
              gA + ss * BKB + j * 32),
          (__attribute__((address_space(3))) uint32_t*)(
              &lds[buf][(wv * 2 + j) * 1024 + l * 16]),
          16, 0, 0);
    }
  };
  // stage B of step ss into buf: kslices (ss*2+j) -> 16384 + (wv*2+j)*1024
  auto stageB2 = [&](int buf, int ss) {
#pragma unroll
    for (int j = 0; j < 2; ++j) {
      __builtin_amdgcn_global_load_lds(
          (const __attribute__((address_space(1))) uint32_t*)(
              gB + ((size_t)(ss * 2 + j) << 10)),
          (__attribute__((address_space(3))) uint32_t*)(
              &lds[buf][16384 + (wv * 2 + j) * 1024 + l * 16]),
          16, 0, 0);
    }
  };

#define PHASE_OPEN()                                    \
  __builtin_amdgcn_s_barrier();                         \
  asm volatile("s_waitcnt lgkmcnt(0)" ::: "memory");    \
  __builtin_amdgcn_sched_barrier(0);                    \
  __builtin_amdgcn_s_setprio(1);

#define PHASE_CLOSE()                                   \
  __builtin_amdgcn_s_setprio(0);

  // prologue: stage steps 0 (buf0) and 1 (buf1); retire step-0's 4 glds
  stageA2(0, 0);
  stageB2(0, 0);
  stageA2(1, 1);
  stageB2(1, 1);
  asm volatile("s_waitcnt vmcnt(4)" ::: "memory");
  __builtin_amdgcn_s_barrier();

  for (int su = 0; su < 16; ++su) {  // 64 steps = 16 x 4 (buf compile-time)
#pragma unroll
    for (int u = 0; u < 4; ++u) {
      const int s = su * 4 + u;
      const int sbuf = (u + 2) & 3;      // compile-time
      const int ss = (s + 2) & 63;       // wrapped; tail writes dead buffers
      const uint8_t* aB = &lds[u][wm * 8192 + l * 16];
      const uint8_t* bB = &lds[u][16384 + wn * 4096 + l * 16];

      // ---- Phase 1: m0,m1 x n0,n1 x ks0,ks1 ----
      int32x4 a[2][2], b[2][2];  // [m][ks], [n][ks]
#pragma unroll
      for (int m = 0; m < 2; ++m)
#pragma unroll
        for (int ks = 0; ks < 2; ++ks)
          a[m][ks] = *(const int32x4*)(aB + m * 2048 + ks * 1024);
#pragma unroll
      for (int n = 0; n < 2; ++n)
#pragma unroll
        for (int ks = 0; ks < 2; ++ks)
          b[n][ks] = *(const int32x4*)(bB + n * 2048 + ks * 1024);
      stageA2(sbuf, ss);
      PHASE_OPEN()
#pragma unroll
      for (int ks = 0; ks < 2; ++ks)
#pragma unroll
        for (int m = 0; m < 2; ++m)
#pragma unroll
          for (int n = 0; n < 2; ++n)
            acc[m][n] = __builtin_amdgcn_mfma_i32_32x32x32_i8(
                a[m][ks], b[n][ks], acc[m][n], 0, 0, 0);
      PHASE_CLOSE()
      __builtin_amdgcn_s_barrier();

      // ---- Phase 2: m2,m3 x n0,n1 x ks0,ks1 (b reused in regs) ----
      int32x4 c[2][2];
#pragma unroll
      for (int m = 0; m < 2; ++m)
#pragma unroll
        for (int ks = 0; ks < 2; ++ks)
          c[m][ks] = *(const int32x4*)(aB + (2 + m) * 2048 + ks * 1024);
      stageB2(sbuf, ss);
      PHASE_OPEN()
#pragma unroll
      for (int ks = 0; ks < 2; ++ks)
#pragma unroll
        for (int m = 0; m < 2; ++m)
#pragma unroll
          for (int n = 0; n < 2; ++n)
            acc[2 + m][n] = __builtin_amdgcn_mfma_i32_32x32x32_i8(
                c[m][ks], b[n][ks], acc[2 + m][n], 0, 0, 0);
      PHASE_CLOSE()
      // retire step-(s+1)'s 4 glds; step-(s+2)'s stay in flight
      asm volatile("s_waitcnt vmcnt(4)" ::: "memory");
      __builtin_amdgcn_s_barrier();
    }
  }
  asm volatile("s_waitcnt vmcnt(0)" ::: "memory");  // drain dead prefetches

#undef PHASE_OPEN
#undef PHASE_CLOSE

  // epilogue: dequant + fp16-round, write f32
  const int colbase = tn + wn * 64;
  const int rowbase = tm + wm * 128 + 4 * (l >> 5);
#pragma unroll
  for (int m = 0; m < 4; ++m) {
#pragma unroll
    for (int n = 0; n < 2; ++n) {
      const int col = colbase + n * 32 + (l & 31);
      const float wsc = wscale[col];
#pragma unroll
      for (int j = 0; j < 16; ++j) {
        const int row = rowbase + m * 32 + (j & 3) + 8 * (j >> 2);
        const float val = (float)acc[m][n][j] * (xs[row] * wsc);
        out[(size_t)row * N_OUT + col] = __half2float(__float2half(val));
      }
    }
  }
}

extern "C" void kernel_launch(void* const* d_in, const int* in_sizes, int n_in,
                              void* d_out, int out_size, void* d_ws, size_t ws_size,
                              hipStream_t stream) {
  const float* x = (const float*)d_in[0];    // fp16 values as f32
  const int* w = (const int*)d_in[1];        // int4-range values as i32
  const float* wsc = (const float*)d_in[2];  // fp16 values as f32
  float* out = (float*)d_out;

  const int M = in_sizes[0] / K_DIM;  // 8192 tokens

  uint8_t* ws = (uint8_t*)d_ws;
  int8_t* xq = (int8_t*)ws;                              // M*K bytes
  uint8_t* wqf = ws + (size_t)M * K_DIM;                 // N*K bytes (frag-major)
  float* xs = (float*)(ws + (size_t)M * K_DIM + (size_t)N_OUT * K_DIM);

  const int packBlocks = N_OUT * K_DIM / 16 / 256;  // 4096
  quant_pack<<<M + packBlocks, 256, 0, stream>>>(x, w, xq, xs,
                                                 (uint32_t*)wqf, M);
  gemm_w4a4<<<(M / BM) * (N_OUT / BN), 512, 0, stream>>>(
      xq, wqf, xs, wsc, out, M);
}